// Round 1
// baseline (149.704 us; speedup 1.0000x reference)
//
#include <hip/hip_runtime.h>
#include <math.h>

#define LOG2E 1.4426950408889634f

typedef _Float16 h2v __attribute__((ext_vector_type(2)));
typedef _Float16 h4  __attribute__((ext_vector_type(4)));
typedef _Float16 h8  __attribute__((ext_vector_type(8)));
typedef float    f4  __attribute__((ext_vector_type(4)));

__device__ __forceinline__ h2v pk(float a, float b) {
    return __builtin_bit_cast(h2v, __builtin_amdgcn_cvt_pkrtz(a, b));
}

__device__ __forceinline__ f4 mfma16x32(h8 a, h8 b, f4 c) {
    return __builtin_amdgcn_mfma_f32_16x16x32_f16(a, b, c, 0, 0, 0);
}

// Legacy (pre-gfx950) intrinsic name has NO underscore before f16.
__device__ __forceinline__ f4 mfma16x16(h4 a, h4 b, f4 c) {
    return __builtin_amdgcn_mfma_f32_16x16x16f16(a, b, c, 0, 0, 0);
}

__device__ __forceinline__ float fast_tanh(float x) {
    const float xc = fminf(fmaxf(x, -15.f), 15.f);
    const float t = exp2f(xc * (2.f * LOG2E));
    return (t - 1.f) * __builtin_amdgcn_rcpf(t + 1.f);
}

// ---------------------------------------------------------------------------
// Prelude: pack conv weights. w2f/w3f in MFMA A-fragment order (fp16);
// w1 as (col0,col1) h2 pairs + fp32 col2 for the conv1 dot2 path.
// Also zeroes the BN arrival counter (workspace is poisoned each replay).
// ---------------------------------------------------------------------------
__global__ __launch_bounds__(256) void k_pack(
    const float* __restrict__ w1,
    const float* __restrict__ w2, const float* __restrict__ w3,
    _Float16* __restrict__ w2f, _Float16* __restrict__ w3f,
    h2v* __restrict__ w1p, float* __restrict__ w1t,
    unsigned* __restrict__ cnt)
{
    if (threadIdx.x == 0) *cnt = 0u;
    if (threadIdx.x < 24) {
        const int oc = threadIdx.x / 3, ky = threadIdx.x % 3;
        w1p[threadIdx.x] = pk(w1[oc * 9 + ky * 3 + 0], w1[oc * 9 + ky * 3 + 1]);
        w1t[threadIdx.x] = w1[oc * 9 + ky * 3 + 2];
    }
    for (int idx = threadIdx.x; idx < 1536; idx += 256) {
        const int j = idx & 7;
        const int lane = (idx >> 3) & 63;
        const int c = idx >> 9;
        const int oc = lane & 15;
        const int s = c * 4 + (lane >> 4);
        w2f[idx] = (s < 9) ? (_Float16)w2[oc * 72 + j * 9 + s] : (_Float16)0.f;
    }
    for (int idx = threadIdx.x; idx < 5120; idx += 256) {
        const int j = idx & 7;
        const int lane = (idx >> 3) & 63;
        const int rest = idx >> 9;          // mt*5 + c
        const int mt = rest / 5;
        const int oc = mt * 16 + (lane & 15);
        const int kk = (lane >> 4) * 8 + j;
        const int ic = kk & 15;
        const int sh = (rest - mt * 5) * 2 + (kk >> 4);
        w3f[idx] = (sh < 9) ? (_Float16)w3[oc * 144 + ic * 9 + sh] : (_Float16)0.f;
    }
}

// ---------------------------------------------------------------------------
// Kernel 1 v9: per-image CNN. conv2/conv3 MFMA B-fragments read DIRECTLY
// from the p1c/p2hc cell arrays. Tail (mean+MLP+q/k/g) now runs on wave 0
// ONLY, fully shuffle-based: barriers 7 -> 4, waves 1-3 retire early.
// ---------------------------------------------------------------------------
__global__ __launch_bounds__(256) void k_cnn(
    const float* __restrict__ x,
    const h2v* __restrict__ w1p, const float* __restrict__ w1t,
    const float* __restrict__ b1,
    const _Float16* __restrict__ w2f, const float* __restrict__ b2,
    const _Float16* __restrict__ w3f, const float* __restrict__ b3,
    const float* __restrict__ gw1,
    const float* __restrict__ gw2,
    const float* __restrict__ rot,
    const float* __restrict__ ent,
    _Float16* __restrict__ q16, _Float16* __restrict__ k16,
    _Float16* __restrict__ g16, _Float16* __restrict__ gswz)
{
    __shared__ __align__(16) char smem[4624 + 5184 + 3200 + 256];
    float* xs   = (float*)smem;                       // 34x34 fp32
    h8*  p1c    = (h8*)(smem + 4624);                 // [18][18] cells of 8 halves
    h8*  p2hc   = (h8*)(smem + 4624 + 5184);          // [10][10] cells, 2 h8 each
    h4*  p2h4   = (h4*)(smem + 4624 + 5184);
    float* fsum = (float*)(smem + 4624 + 5184 + 3200);    // 64 floats

    const int t = threadIdx.x;
    const int b = blockIdx.x;
    const int lane = t & 63;
    const int w = __builtin_amdgcn_readfirstlane(t >> 6);
    const int nn = lane & 15;
    const int kq = lane >> 4;

    const h8 hzero = (h8)(_Float16)0.f;
    const f4 fzero = {0.f, 0.f, 0.f, 0.f};

    // ---- halo-only zeroing (interiors fully overwritten) ----
    if (t < 132) {
        int r, c;
        if (t < 34)       { r = 0;  c = t; }
        else if (t < 68)  { r = 33; c = t - 34; }
        else if (t < 100) { r = t - 68 + 1;  c = 0; }
        else              { r = t - 100 + 1; c = 33; }
        xs[r * 34 + c] = 0.f;
    } else if (t < 200) {
        const int u = t - 132;
        int r, c;
        if (u < 18)      { r = 0;  c = u; }
        else if (u < 36) { r = 17; c = u - 18; }
        else if (u < 52) { r = u - 36 + 1; c = 0; }
        else             { r = u - 52 + 1; c = 17; }
        p1c[r * 18 + c] = hzero;
    } else if (t < 236) {
        const int u = t - 200;
        int r, c;
        if (u < 10)      { r = 0; c = u; }
        else if (u < 20) { r = 9; c = u - 10; }
        else if (u < 28) { r = u - 20 + 1; c = 0; }
        else             { r = u - 28 + 1; c = 9; }
        p2hc[(r * 10 + c) * 2 + 0] = hzero;
        p2hc[(r * 10 + c) * 2 + 1] = hzero;
    }
    {
        const float4 v = ((const float4*)(x + (size_t)b * 1024))[t];
        const int row = t >> 3;
        const int col = (t & 7) << 2;
        float* dst = &xs[(row + 1) * 34 + col + 1];
        dst[0] = v.x; dst[1] = v.y; dst[2] = v.z; dst[3] = v.w;
    }
    __syncthreads();

    // ---- stage 1: conv1 via fdot2 + relu + maxpool2 -> p1 cells ----
    {
        const int px = t & 15, py = t >> 4;
        float pa[4][4];
        #pragma unroll
        for (int iy = 0; iy < 4; ++iy)
            #pragma unroll
            for (int ix = 0; ix < 4; ++ix)
                pa[iy][ix] = xs[(2 * py + iy) * 34 + (2 * px + ix)];
        h2v pA[4], pB[4];
        #pragma unroll
        for (int r = 0; r < 4; ++r) {
            pA[r] = pk(pa[r][0], pa[r][1]);
            pB[r] = pk(pa[r][1], pa[r][2]);
        }

        float r8[8];
        #pragma unroll
        for (int oc = 0; oc < 8; ++oc) {
            const h2v wp0 = w1p[oc * 3 + 0], wp1 = w1p[oc * 3 + 1], wp2 = w1p[oc * 3 + 2];
            const float wt0 = w1t[oc * 3 + 0], wt1 = w1t[oc * 3 + 1], wt2 = w1t[oc * 3 + 2];
            const float bb = b1[oc];
            float mx = -1e30f;
            #pragma unroll
            for (int sy = 0; sy < 2; ++sy) {
                float s0 = bb, s1 = bb;
                s0 = __builtin_amdgcn_fdot2(pA[sy],     wp0, s0, false);
                s0 = __builtin_amdgcn_fdot2(pA[sy + 1], wp1, s0, false);
                s0 = __builtin_amdgcn_fdot2(pA[sy + 2], wp2, s0, false);
                s0 = fmaf(pa[sy][2], wt0, s0);
                s0 = fmaf(pa[sy + 1][2], wt1, s0);
                s0 = fmaf(pa[sy + 2][2], wt2, s0);
                s1 = __builtin_amdgcn_fdot2(pB[sy],     wp0, s1, false);
                s1 = __builtin_amdgcn_fdot2(pB[sy + 1], wp1, s1, false);
                s1 = __builtin_amdgcn_fdot2(pB[sy + 2], wp2, s1, false);
                s1 = fmaf(pa[sy][3], wt0, s1);
                s1 = fmaf(pa[sy + 1][3], wt1, s1);
                s1 = fmaf(pa[sy + 2][3], wt2, s1);
                mx = fmaxf(mx, fmaxf(s0, s1));
            }
            r8[oc] = fmaxf(mx, 0.f);
        }
        union { h8 v; h2v p[4]; } u;
        #pragma unroll
        for (int ocp = 0; ocp < 4; ++ocp) u.p[ocp] = pk(r8[2 * ocp], r8[2 * ocp + 1]);
        p1c[(py + 1) * 18 + (px + 1)] = u.v;
    }

    h8 a2[3];
    #pragma unroll
    for (int c = 0; c < 3; ++c) a2[c] = ((const h8*)w2f)[c * 64 + lane];

    __syncthreads();   // p1c ready

    // ---- conv2(8->16) as GEMM: B-fragments read directly from p1c ----
    f4 accp[4] = {fzero, fzero, fzero, fzero};
    #pragma unroll
    for (int c = 0; c < 3; ++c) {
        const int s = c * 4 + kq;
        const int ky = (s < 9) ? s / 3 : 0;
        const int kx = (s < 9) ? s % 3 : 0;
        #pragma unroll
        for (int p = 0; p < 4; ++p) {
            h8 bf = hzero;
            if (s < 9) bf = p1c[(4 * w + p + ky) * 18 + (nn + kx)];
            accp[p] = mfma16x32(a2[c], bf, accp[p]);
        }
    }

    // ---- conv2 epilogue: +bias, relu, 2x2 maxpool -> p2 cells ----
    {
        float bq[4];
        #pragma unroll
        for (int r = 0; r < 4; ++r) bq[r] = b2[kq * 4 + r];
        #pragma unroll
        for (int i = 0; i < 2; ++i) {
            float m2[4];
            #pragma unroll
            for (int r = 0; r < 4; ++r) {
                const float v0 = fmaxf(accp[2 * i][r] + bq[r], 0.f);
                const float v1 = fmaxf(accp[2 * i + 1][r] + bq[r], 0.f);
                float mv = fmaxf(v0, v1);
                mv = fmaxf(mv, __shfl_xor(mv, 1));
                m2[r] = mv;
            }
            if ((lane & 1) == 0) {
                const int px = nn >> 1;
                const int py = 2 * w + i;
                union { h4 v; h2v p[2]; } u;
                u.p[0] = pk(m2[0], m2[1]);
                u.p[1] = pk(m2[2], m2[3]);
                p2h4[((py + 1) * 10 + (px + 1)) * 4 + kq] = u.v;
            }
        }
    }

    const int mt = w >> 1;
    const int nt0 = (w & 1) * 2;
    h8 a3[5];
    #pragma unroll
    for (int c = 0; c < 5; ++c) a3[c] = ((const h8*)w3f)[(mt * 5 + c) * 64 + lane];

    __syncthreads();   // p2hc ready

    // ---- conv3(16->32) as GEMM: B-fragments read directly from p2hc ----
    f4 acc3[2] = {fzero, fzero};
    #pragma unroll
    for (int c = 0; c < 5; ++c) {
        const int shv = 2 * c + (kq >> 1);
        const int hh = kq & 1;
        const int ky = (shv < 9) ? ((shv * 11) >> 5) : 0;
        const int kx = (shv < 9) ? (shv - 3 * ky) : 0;
        #pragma unroll
        for (int p = 0; p < 2; ++p) {
            const int pos = (nt0 + p) * 16 + nn;
            const int yy = pos >> 3, xx = pos & 7;
            h8 bf = hzero;
            if (shv < 9) bf = p2hc[((yy + ky) * 10 + (xx + kx)) * 2 + hh];
            acc3[p] = mfma16x32(a3[c], bf, acc3[p]);
        }
    }

    // ---- conv3 epilogue: +bias, relu, spatial sum ----
    {
        float bq[4];
        #pragma unroll
        for (int r = 0; r < 4; ++r) bq[r] = b3[mt * 16 + kq * 4 + r];
        float sv[4];
        #pragma unroll
        for (int r = 0; r < 4; ++r) {
            float s = fmaxf(acc3[0][r] + bq[r], 0.f) + fmaxf(acc3[1][r] + bq[r], 0.f);
            #pragma unroll
            for (int off = 1; off < 16; off <<= 1) s += __shfl_xor(s, off);
            sv[r] = s;
        }
        if (nn == 0) {
            const f4 pack = {sv[0], sv[1], sv[2], sv[3]};
            ((f4*)fsum)[mt * 8 + (w & 1) * 4 + kq] = pack;
        }
    }
    __syncthreads();   // fsum ready

    // ---- wave-0-only tail: mean + MLP head, shuffle-based, no barriers ----
    if (w != 0) return;

    const int l = t;                 // 0..63
    const int i5 = l & 31;
    // fs: per-channel mean (channels 0..31 held by lanes l&31)
    const float fsv = (fsum[(i5 >> 4) * 32 + (i5 & 15)] +
                       fsum[(i5 >> 4) * 32 + 16 + (i5 & 15)]) * (1.f / 64.f);

    // as = tanh(gw1 @ fs): 32 outputs, j-range split across lane halves
    float asv;
    {
        const int h = l >> 5;        // 0 or 1
        float s = 0.f;
        #pragma unroll
        for (int q4 = 0; q4 < 4; ++q4) {
            const float4 wv = ((const float4*)gw1)[i5 * 8 + h * 4 + q4];
            s = fmaf(wv.x, __shfl(fsv, h * 16 + q4 * 4 + 0), s);
            s = fmaf(wv.y, __shfl(fsv, h * 16 + q4 * 4 + 1), s);
            s = fmaf(wv.z, __shfl(fsv, h * 16 + q4 * 4 + 2), s);
            s = fmaf(wv.w, __shfl(fsv, h * 16 + q4 * 4 + 3), s);
        }
        s += __shfl_xor(s, 32);      // all lanes now hold as_{l&31}
        asv = fast_tanh(s);
    }

    // gs = tanh(gw2 @ as): 16 outputs, j-range split across lane quads
    const int i4 = l & 15;
    float gsv;
    {
        const int h = l >> 4;        // 0..3
        float s = 0.f;
        #pragma unroll
        for (int q4 = 0; q4 < 2; ++q4) {
            const float4 wv = ((const float4*)gw2)[i4 * 8 + h * 2 + q4];
            s = fmaf(wv.x, __shfl(asv, h * 8 + q4 * 4 + 0), s);
            s = fmaf(wv.y, __shfl(asv, h * 8 + q4 * 4 + 1), s);
            s = fmaf(wv.z, __shfl(asv, h * 8 + q4 * 4 + 2), s);
            s = fmaf(wv.w, __shfl(asv, h * 8 + q4 * 4 + 3), s);
        }
        s += __shfl_xor(s, 16);
        s += __shfl_xor(s, 32);      // all lanes now hold gs_{l&15}
        gsv = fast_tanh(s);
    }

    // final: grp0 -> q16 (scaled), grp1 -> k16, grp2 -> g16, grp3 -> gswz.
    // All shuffles executed convergently (before/outside divergent stores).
    const int grp = l >> 4;
    const int r = i4 >> 2, c = i4 & 3;
    float gq[4];
    #pragma unroll
    for (int j = 0; j < 4; ++j) gq[j] = __shfl(gsv, r * 4 + j);
    const float temp = (cosf(ent[0]) + cosf(ent[1]) + cosf(ent[2])) * (1.f / 3.f);

    float v;
    if (grp == 0) {
        v = 0.f;
        #pragma unroll
        for (int j = 0; j < 4; ++j) v = fmaf(gq[j], rot[j * 4 + c], v);
        v *= temp * 0.25f;
    } else if (grp == 1) {
        v = 0.f;
        #pragma unroll
        for (int j = 0; j < 4; ++j) v = fmaf(gq[j], rot[c * 4 + j], v);
    } else {
        v = gsv;
    }
    const float vn = __shfl_xor(v, 1);   // convergent pair exchange

    if (grp == 3) {
        const int tile = b >> 4, lc = b & 15;
        gswz[tile * 256 + (((lc >> 2) * 16) + i4) * 4 + (lc & 3)] = (_Float16)gsv;
    } else if ((i4 & 1) == 0) {
        const h2v pv = pk(v, vn);
        if (grp == 0)      ((h2v*)q16)[b * 8 + (i4 >> 1)] = pv;
        else if (grp == 1) ((h2v*)k16)[b * 8 + (i4 >> 1)] = pv;
        else               ((h2v*)g16)[b * 8 + (i4 >> 1)] = pv;
    }
}

// ---------------------------------------------------------------------------
// Kernel 2 v6: MFMA flash attention, 16 waves/block, with BatchNorm1d fused
// via the "last block applies" pattern (deadlock-free, counter in ws).
// ---------------------------------------------------------------------------
__global__ __launch_bounds__(1024) void k_attn(
    const _Float16* __restrict__ q16, const _Float16* __restrict__ k16,
    const _Float16* __restrict__ g16, const _Float16* __restrict__ gswz,
    const float* __restrict__ rw, const float* __restrict__ rb,
    const float* __restrict__ cw, const float* __restrict__ cb,
    const float* __restrict__ gamma, const float* __restrict__ beta,
    float* __restrict__ outp, unsigned* __restrict__ cnt, int B)
{
    __shared__ f4 lO[16][64];
    __shared__ float lm[16][16];
    __shared__ float ll[16][16];
    __shared__ unsigned lastFlag;

    const int t = threadIdx.x;
    const int lane = t & 63;
    const int w = t >> 6;
    const int rt = blockIdx.x;
    const int r = lane & 15;
    const int q = lane >> 4;
    const f4 fzero = {0.f, 0.f, 0.f, 0.f};

    const h4 qf = *(const h4*)(q16 + ((size_t)(rt * 16 + r)) * 16 + q * 4);

    float m = -1e30f, lp = 0.f;
    f4 O = fzero;

    const int strip = B >> 4;
    const int cbeg = w * strip;
    for (int ci = 0; ci < strip; ci += 16) {
        const int c0 = cbeg + ci;
        const h4 kf = *(const h4*)(k16 + ((size_t)(c0 + r)) * 16 + q * 4);
        const f4 st = mfma16x16(kf, qf, fzero);

        float mx = fmaxf(fmaxf(st[0], st[1]), fmaxf(st[2], st[3]));
        mx = fmaxf(mx, __shfl_xor(mx, 16));
        mx = fmaxf(mx, __shfl_xor(mx, 32));
        if (__ballot(mx > m)) {
            const float mn = fmaxf(m, mx);
            const float a = exp2f((m - mn) * LOG2E);
            lp *= a;
            O[0] *= a; O[1] *= a; O[2] *= a; O[3] *= a;
            m = mn;
        }
        const float p0 = exp2f((st[0] - m) * LOG2E);
        const float p1 = exp2f((st[1] - m) * LOG2E);
        const float p2 = exp2f((st[2] - m) * LOG2E);
        const float p3 = exp2f((st[3] - m) * LOG2E);
        lp += (p0 + p1) + (p2 + p3);

        union { h4 v; h2v p[2]; } u;
        u.p[0] = pk(p0, p1);
        u.p[1] = pk(p2, p3);
        const h4 gf = *(const h4*)(gswz + (size_t)((c0 >> 4)) * 256 + lane * 4);
        O = mfma16x16(gf, u.v, O);
    }
    lp += __shfl_xor(lp, 16);
    lp += __shfl_xor(lp, 32);

    lO[w][lane] = O;
    if (lane < 16) { lm[w][lane] = m; ll[w][lane] = lp; }
    __syncthreads();

    if (w == 0) {
        float M = lm[0][r];
        #pragma unroll
        for (int ww = 1; ww < 16; ++ww) M = fmaxf(M, lm[ww][r]);
        float L = 0.f;
        f4 Om = fzero;
        #pragma unroll
        for (int ww = 0; ww < 16; ++ww) {
            const float f = exp2f((lm[ww][r] - M) * LOG2E);
            L = fmaf(ll[ww][r], f, L);
            const f4 ow = lO[ww][lane];
            Om[0] = fmaf(ow[0], f, Om[0]);
            Om[1] = fmaf(ow[1], f, Om[1]);
            Om[2] = fmaf(ow[2], f, Om[2]);
            Om[3] = fmaf(ow[3], f, Om[3]);
        }
        const float il = 1.f / L;
        const h4 gr = *(const h4*)(g16 + ((size_t)(rt * 16 + r)) * 16 + q * 4);

        float rv[2];
        #pragma unroll
        for (int c = 0; c < 2; ++c) {
            float s = 0.f;
            #pragma unroll
            for (int j = 0; j < 4; ++j) {
                s = fmaf((float)gr[j], rw[c * 32 + q * 4 + j], s);
                s = fmaf(Om[j] * il, rw[c * 32 + 16 + q * 4 + j], s);
            }
            s += __shfl_xor(s, 16);
            s += __shfl_xor(s, 32);
            rv[c] = s + rb[c];
        }
        if (q == 0) {
            float2 o;
            o.x = cb[0] + cw[0] * rv[0] + cw[1] * rv[1];
            o.y = cb[1] + cw[2] * rv[0] + cw[3] * rv[1];
            ((float2*)outp)[rt * 16 + r] = o;
        }
    }

    // ---- fused BatchNorm1d(2): last arriving block applies batch stats ----
    if (t == 0) {
        __threadfence();   // release: make this block's raw rows visible
        const unsigned old = __hip_atomic_fetch_add(
            cnt, 1u, __ATOMIC_ACQ_REL, __HIP_MEMORY_SCOPE_AGENT);
        lastFlag = (old == (unsigned)gridDim.x - 1u) ? 1u : 0u;
    }
    __syncthreads();
    if (!lastFlag) return;
    __threadfence();       // acquire: invalidate stale cached lines

    float* red  = (float*)lm;   // reuse: 16 waves x 4 partials
    float* coef = (float*)ll;   // reuse: 4 coefficients

    float s0 = 0.f, s1 = 0.f, q0 = 0.f, q1 = 0.f;
    for (int i = t; i < B; i += 1024) {
        const float2 v = ((const float2*)outp)[i];
        s0 += v.x; q0 += v.x * v.x;
        s1 += v.y; q1 += v.y * v.y;
    }
    #pragma unroll
    for (int off = 32; off; off >>= 1) {
        s0 += __shfl_xor(s0, off); q0 += __shfl_xor(q0, off);
        s1 += __shfl_xor(s1, off); q1 += __shfl_xor(q1, off);
    }
    if ((t & 63) == 0) {
        red[(t >> 6) * 4 + 0] = s0; red[(t >> 6) * 4 + 1] = q0;
        red[(t >> 6) * 4 + 2] = s1; red[(t >> 6) * 4 + 3] = q1;
    }
    __syncthreads();
    if (t == 0) {
        float S0 = 0.f, Q0 = 0.f, S1 = 0.f, Q1 = 0.f;
        for (int ww = 0; ww < 16; ++ww) {
            S0 += red[ww * 4 + 0]; Q0 += red[ww * 4 + 1];
            S1 += red[ww * 4 + 2]; Q1 += red[ww * 4 + 3];
        }
        const float inv = 1.f / (float)B;
        const float mu0 = S0 * inv, mu1 = S1 * inv;
        const float v0 = Q0 * inv - mu0 * mu0;
        const float v1 = Q1 * inv - mu1 * mu1;
        const float sc0 = gamma[0] * rsqrtf(v0 + 1e-5f);
        const float sc1 = gamma[1] * rsqrtf(v1 + 1e-5f);
        coef[0] = sc0; coef[1] = beta[0] - mu0 * sc0;
        coef[2] = sc1; coef[3] = beta[1] - mu1 * sc1;
    }
    __syncthreads();
    const float sc0 = coef[0], sh0 = coef[1], sc1 = coef[2], sh1 = coef[3];
    for (int i = t; i < B; i += 1024) {
        float2 v = ((const float2*)outp)[i];
        v.x = fmaf(v.x, sc0, sh0);
        v.y = fmaf(v.y, sc1, sh1);
        ((float2*)outp)[i] = v;
    }
}

extern "C" void kernel_launch(void* const* d_in, const int* in_sizes, int n_in,
                              void* d_out, int out_size, void* d_ws, size_t ws_size,
                              hipStream_t stream)
{
    (void)n_in; (void)out_size; (void)ws_size;
    const float* x   = (const float*)d_in[0];
    const float* w1  = (const float*)d_in[1];
    const float* b1  = (const float*)d_in[2];
    const float* w2  = (const float*)d_in[3];
    const float* b2  = (const float*)d_in[4];
    const float* w3  = (const float*)d_in[5];
    const float* b3  = (const float*)d_in[6];
    const float* gw1 = (const float*)d_in[7];
    const float* gw2 = (const float*)d_in[8];
    const float* rot = (const float*)d_in[9];
    const float* ent = (const float*)d_in[10];
    const float* rw  = (const float*)d_in[11];
    const float* rbv = (const float*)d_in[12];
    const float* cw  = (const float*)d_in[13];
    const float* cbv = (const float*)d_in[14];
    const float* gam = (const float*)d_in[15];
    const float* bet = (const float*)d_in[16];

    const int B = in_sizes[0] / (32 * 32);   // 4096

    _Float16* q16  = (_Float16*)d_ws;                 // [B][16]
    _Float16* k16  = q16 + (size_t)B * 16;            // [B][16]
    _Float16* g16  = k16 + (size_t)B * 16;            // [B][16]
    _Float16* gswz = g16 + (size_t)B * 16;            // [B/16][64][4]
    _Float16* w2f  = gswz + (size_t)B * 16;           // 1536 halves
    _Float16* w3f  = w2f + 1536;                      // 5120 halves
    h2v*      w1p  = (h2v*)(w3f + 5120);              // 24 pairs
    float*    w1t  = (float*)(w1p + 24);              // 24 floats
    unsigned* cnt  = (unsigned*)(w1t + 24);           // BN arrival counter
    float* pre = (float*)d_out;

    k_pack<<<1, 256, 0, stream>>>(w1, w2, w3, w2f, w3f, w1p, w1t, cnt);
    k_cnn<<<B, 256, 0, stream>>>(x, w1p, w1t, b1, w2f, b2, w3f, b3, gw1, gw2,
                                 rot, ent, q16, k16, g16, gswz);
    k_attn<<<B / 16, 1024, 0, stream>>>(q16, k16, g16, gswz, rw, rbv, cw, cbv,
                                        gam, bet, pre, cnt, B);
}

// Round 2
// 140.332 us; speedup vs baseline: 1.0668x; 1.0668x over previous
//
#include <hip/hip_runtime.h>
#include <math.h>

#define LOG2E 1.4426950408889634f

typedef _Float16 h2v __attribute__((ext_vector_type(2)));
typedef _Float16 h4  __attribute__((ext_vector_type(4)));
typedef _Float16 h8  __attribute__((ext_vector_type(8)));
typedef float    f4  __attribute__((ext_vector_type(4)));

__device__ __forceinline__ h2v pk(float a, float b) {
    return __builtin_bit_cast(h2v, __builtin_amdgcn_cvt_pkrtz(a, b));
}

__device__ __forceinline__ f4 mfma16x32(h8 a, h8 b, f4 c) {
    return __builtin_amdgcn_mfma_f32_16x16x32_f16(a, b, c, 0, 0, 0);
}

// Legacy (pre-gfx950) intrinsic name has NO underscore before f16.
__device__ __forceinline__ f4 mfma16x16(h4 a, h4 b, f4 c) {
    return __builtin_amdgcn_mfma_f32_16x16x16f16(a, b, c, 0, 0, 0);
}

__device__ __forceinline__ float fast_tanh(float x) {
    const float xc = fminf(fmaxf(x, -15.f), 15.f);
    const float t = exp2f(xc * (2.f * LOG2E));
    return (t - 1.f) * __builtin_amdgcn_rcpf(t + 1.f);
}

// ---------------------------------------------------------------------------
// Prelude: pack conv weights. w2f/w3f in MFMA A-fragment order (fp16);
// w1 as (col0,col1) h2 pairs + fp32 col2 for the conv1 dot2 path.
// ---------------------------------------------------------------------------
__global__ __launch_bounds__(256) void k_pack(
    const float* __restrict__ w1,
    const float* __restrict__ w2, const float* __restrict__ w3,
    _Float16* __restrict__ w2f, _Float16* __restrict__ w3f,
    h2v* __restrict__ w1p, float* __restrict__ w1t)
{
    if (threadIdx.x < 24) {
        const int oc = threadIdx.x / 3, ky = threadIdx.x % 3;
        w1p[threadIdx.x] = pk(w1[oc * 9 + ky * 3 + 0], w1[oc * 9 + ky * 3 + 1]);
        w1t[threadIdx.x] = w1[oc * 9 + ky * 3 + 2];
    }
    for (int idx = threadIdx.x; idx < 1536; idx += 256) {
        const int j = idx & 7;
        const int lane = (idx >> 3) & 63;
        const int c = idx >> 9;
        const int oc = lane & 15;
        const int s = c * 4 + (lane >> 4);
        w2f[idx] = (s < 9) ? (_Float16)w2[oc * 72 + j * 9 + s] : (_Float16)0.f;
    }
    for (int idx = threadIdx.x; idx < 5120; idx += 256) {
        const int j = idx & 7;
        const int lane = (idx >> 3) & 63;
        const int rest = idx >> 9;          // mt*5 + c
        const int mt = rest / 5;
        const int oc = mt * 16 + (lane & 15);
        const int kk = (lane >> 4) * 8 + j;
        const int ic = kk & 15;
        const int sh = (rest - mt * 5) * 2 + (kk >> 4);
        w3f[idx] = (sh < 9) ? (_Float16)w3[oc * 144 + ic * 9 + sh] : (_Float16)0.f;
    }
}

// ---------------------------------------------------------------------------
// Kernel 1 v9: per-image CNN. conv2/conv3 MFMA B-fragments read DIRECTLY
// from the p1c/p2hc cell arrays. Tail (mean+MLP+q/k/g) runs on wave 0
// ONLY, fully shuffle-based: barriers 7 -> 4, waves 1-3 retire early.
// ---------------------------------------------------------------------------
__global__ __launch_bounds__(256) void k_cnn(
    const float* __restrict__ x,
    const h2v* __restrict__ w1p, const float* __restrict__ w1t,
    const float* __restrict__ b1,
    const _Float16* __restrict__ w2f, const float* __restrict__ b2,
    const _Float16* __restrict__ w3f, const float* __restrict__ b3,
    const float* __restrict__ gw1,
    const float* __restrict__ gw2,
    const float* __restrict__ rot,
    const float* __restrict__ ent,
    _Float16* __restrict__ q16, _Float16* __restrict__ k16,
    _Float16* __restrict__ g16, _Float16* __restrict__ gswz)
{
    __shared__ __align__(16) char smem[4624 + 5184 + 3200 + 256];
    float* xs   = (float*)smem;                       // 34x34 fp32
    h8*  p1c    = (h8*)(smem + 4624);                 // [18][18] cells of 8 halves
    h8*  p2hc   = (h8*)(smem + 4624 + 5184);          // [10][10] cells, 2 h8 each
    h4*  p2h4   = (h4*)(smem + 4624 + 5184);
    float* fsum = (float*)(smem + 4624 + 5184 + 3200);    // 64 floats

    const int t = threadIdx.x;
    const int b = blockIdx.x;
    const int lane = t & 63;
    const int w = __builtin_amdgcn_readfirstlane(t >> 6);
    const int nn = lane & 15;
    const int kq = lane >> 4;

    const h8 hzero = (h8)(_Float16)0.f;
    const f4 fzero = {0.f, 0.f, 0.f, 0.f};

    // ---- halo-only zeroing (interiors fully overwritten) ----
    if (t < 132) {
        int r, c;
        if (t < 34)       { r = 0;  c = t; }
        else if (t < 68)  { r = 33; c = t - 34; }
        else if (t < 100) { r = t - 68 + 1;  c = 0; }
        else              { r = t - 100 + 1; c = 33; }
        xs[r * 34 + c] = 0.f;
    } else if (t < 200) {
        const int u = t - 132;
        int r, c;
        if (u < 18)      { r = 0;  c = u; }
        else if (u < 36) { r = 17; c = u - 18; }
        else if (u < 52) { r = u - 36 + 1; c = 0; }
        else             { r = u - 52 + 1; c = 17; }
        p1c[r * 18 + c] = hzero;
    } else if (t < 236) {
        const int u = t - 200;
        int r, c;
        if (u < 10)      { r = 0; c = u; }
        else if (u < 20) { r = 9; c = u - 10; }
        else if (u < 28) { r = u - 20 + 1; c = 0; }
        else             { r = u - 28 + 1; c = 9; }
        p2hc[(r * 10 + c) * 2 + 0] = hzero;
        p2hc[(r * 10 + c) * 2 + 1] = hzero;
    }
    {
        const float4 v = ((const float4*)(x + (size_t)b * 1024))[t];
        const int row = t >> 3;
        const int col = (t & 7) << 2;
        float* dst = &xs[(row + 1) * 34 + col + 1];
        dst[0] = v.x; dst[1] = v.y; dst[2] = v.z; dst[3] = v.w;
    }
    __syncthreads();

    // ---- stage 1: conv1 via fdot2 + relu + maxpool2 -> p1 cells ----
    {
        const int px = t & 15, py = t >> 4;
        float pa[4][4];
        #pragma unroll
        for (int iy = 0; iy < 4; ++iy)
            #pragma unroll
            for (int ix = 0; ix < 4; ++ix)
                pa[iy][ix] = xs[(2 * py + iy) * 34 + (2 * px + ix)];
        h2v pA[4], pB[4];
        #pragma unroll
        for (int r = 0; r < 4; ++r) {
            pA[r] = pk(pa[r][0], pa[r][1]);
            pB[r] = pk(pa[r][1], pa[r][2]);
        }

        float r8[8];
        #pragma unroll
        for (int oc = 0; oc < 8; ++oc) {
            const h2v wp0 = w1p[oc * 3 + 0], wp1 = w1p[oc * 3 + 1], wp2 = w1p[oc * 3 + 2];
            const float wt0 = w1t[oc * 3 + 0], wt1 = w1t[oc * 3 + 1], wt2 = w1t[oc * 3 + 2];
            const float bb = b1[oc];
            float mx = -1e30f;
            #pragma unroll
            for (int sy = 0; sy < 2; ++sy) {
                float s0 = bb, s1 = bb;
                s0 = __builtin_amdgcn_fdot2(pA[sy],     wp0, s0, false);
                s0 = __builtin_amdgcn_fdot2(pA[sy + 1], wp1, s0, false);
                s0 = __builtin_amdgcn_fdot2(pA[sy + 2], wp2, s0, false);
                s0 = fmaf(pa[sy][2], wt0, s0);
                s0 = fmaf(pa[sy + 1][2], wt1, s0);
                s0 = fmaf(pa[sy + 2][2], wt2, s0);
                s1 = __builtin_amdgcn_fdot2(pB[sy],     wp0, s1, false);
                s1 = __builtin_amdgcn_fdot2(pB[sy + 1], wp1, s1, false);
                s1 = __builtin_amdgcn_fdot2(pB[sy + 2], wp2, s1, false);
                s1 = fmaf(pa[sy][3], wt0, s1);
                s1 = fmaf(pa[sy + 1][3], wt1, s1);
                s1 = fmaf(pa[sy + 2][3], wt2, s1);
                mx = fmaxf(mx, fmaxf(s0, s1));
            }
            r8[oc] = fmaxf(mx, 0.f);
        }
        union { h8 v; h2v p[4]; } u;
        #pragma unroll
        for (int ocp = 0; ocp < 4; ++ocp) u.p[ocp] = pk(r8[2 * ocp], r8[2 * ocp + 1]);
        p1c[(py + 1) * 18 + (px + 1)] = u.v;
    }

    h8 a2[3];
    #pragma unroll
    for (int c = 0; c < 3; ++c) a2[c] = ((const h8*)w2f)[c * 64 + lane];

    __syncthreads();   // p1c ready

    // ---- conv2(8->16) as GEMM: B-fragments read directly from p1c ----
    f4 accp[4] = {fzero, fzero, fzero, fzero};
    #pragma unroll
    for (int c = 0; c < 3; ++c) {
        const int s = c * 4 + kq;
        const int ky = (s < 9) ? s / 3 : 0;
        const int kx = (s < 9) ? s % 3 : 0;
        #pragma unroll
        for (int p = 0; p < 4; ++p) {
            h8 bf = hzero;
            if (s < 9) bf = p1c[(4 * w + p + ky) * 18 + (nn + kx)];
            accp[p] = mfma16x32(a2[c], bf, accp[p]);
        }
    }

    // ---- conv2 epilogue: +bias, relu, 2x2 maxpool -> p2 cells ----
    {
        float bq[4];
        #pragma unroll
        for (int r = 0; r < 4; ++r) bq[r] = b2[kq * 4 + r];
        #pragma unroll
        for (int i = 0; i < 2; ++i) {
            float m2[4];
            #pragma unroll
            for (int r = 0; r < 4; ++r) {
                const float v0 = fmaxf(accp[2 * i][r] + bq[r], 0.f);
                const float v1 = fmaxf(accp[2 * i + 1][r] + bq[r], 0.f);
                float mv = fmaxf(v0, v1);
                mv = fmaxf(mv, __shfl_xor(mv, 1));
                m2[r] = mv;
            }
            if ((lane & 1) == 0) {
                const int px = nn >> 1;
                const int py = 2 * w + i;
                union { h4 v; h2v p[2]; } u;
                u.p[0] = pk(m2[0], m2[1]);
                u.p[1] = pk(m2[2], m2[3]);
                p2h4[((py + 1) * 10 + (px + 1)) * 4 + kq] = u.v;
            }
        }
    }

    const int mt = w >> 1;
    const int nt0 = (w & 1) * 2;
    h8 a3[5];
    #pragma unroll
    for (int c = 0; c < 5; ++c) a3[c] = ((const h8*)w3f)[(mt * 5 + c) * 64 + lane];

    __syncthreads();   // p2hc ready

    // ---- conv3(16->32) as GEMM: B-fragments read directly from p2hc ----
    f4 acc3[2] = {fzero, fzero};
    #pragma unroll
    for (int c = 0; c < 5; ++c) {
        const int shv = 2 * c + (kq >> 1);
        const int hh = kq & 1;
        const int ky = (shv < 9) ? ((shv * 11) >> 5) : 0;
        const int kx = (shv < 9) ? (shv - 3 * ky) : 0;
        #pragma unroll
        for (int p = 0; p < 2; ++p) {
            const int pos = (nt0 + p) * 16 + nn;
            const int yy = pos >> 3, xx = pos & 7;
            h8 bf = hzero;
            if (shv < 9) bf = p2hc[((yy + ky) * 10 + (xx + kx)) * 2 + hh];
            acc3[p] = mfma16x32(a3[c], bf, acc3[p]);
        }
    }

    // ---- conv3 epilogue: +bias, relu, spatial sum ----
    {
        float bq[4];
        #pragma unroll
        for (int r = 0; r < 4; ++r) bq[r] = b3[mt * 16 + kq * 4 + r];
        float sv[4];
        #pragma unroll
        for (int r = 0; r < 4; ++r) {
            float s = fmaxf(acc3[0][r] + bq[r], 0.f) + fmaxf(acc3[1][r] + bq[r], 0.f);
            #pragma unroll
            for (int off = 1; off < 16; off <<= 1) s += __shfl_xor(s, off);
            sv[r] = s;
        }
        if (nn == 0) {
            const f4 pack = {sv[0], sv[1], sv[2], sv[3]};
            ((f4*)fsum)[mt * 8 + (w & 1) * 4 + kq] = pack;
        }
    }
    __syncthreads();   // fsum ready

    // ---- wave-0-only tail: mean + MLP head, shuffle-based, no barriers ----
    if (w != 0) return;

    const int l = t;                 // 0..63
    const int i5 = l & 31;
    // fs: per-channel mean (channels 0..31 held by lanes l&31)
    const float fsv = (fsum[(i5 >> 4) * 32 + (i5 & 15)] +
                       fsum[(i5 >> 4) * 32 + 16 + (i5 & 15)]) * (1.f / 64.f);

    // as = tanh(gw1 @ fs): 32 outputs, j-range split across lane halves
    float asv;
    {
        const int h = l >> 5;        // 0 or 1
        float s = 0.f;
        #pragma unroll
        for (int q4 = 0; q4 < 4; ++q4) {
            const float4 wv = ((const float4*)gw1)[i5 * 8 + h * 4 + q4];
            s = fmaf(wv.x, __shfl(fsv, h * 16 + q4 * 4 + 0), s);
            s = fmaf(wv.y, __shfl(fsv, h * 16 + q4 * 4 + 1), s);
            s = fmaf(wv.z, __shfl(fsv, h * 16 + q4 * 4 + 2), s);
            s = fmaf(wv.w, __shfl(fsv, h * 16 + q4 * 4 + 3), s);
        }
        s += __shfl_xor(s, 32);      // all lanes now hold as_{l&31}
        asv = fast_tanh(s);
    }

    // gs = tanh(gw2 @ as): 16 outputs, j-range split across lane quads
    const int i4 = l & 15;
    float gsv;
    {
        const int h = l >> 4;        // 0..3
        float s = 0.f;
        #pragma unroll
        for (int q4 = 0; q4 < 2; ++q4) {
            const float4 wv = ((const float4*)gw2)[i4 * 8 + h * 2 + q4];
            s = fmaf(wv.x, __shfl(asv, h * 8 + q4 * 4 + 0), s);
            s = fmaf(wv.y, __shfl(asv, h * 8 + q4 * 4 + 1), s);
            s = fmaf(wv.z, __shfl(asv, h * 8 + q4 * 4 + 2), s);
            s = fmaf(wv.w, __shfl(asv, h * 8 + q4 * 4 + 3), s);
        }
        s += __shfl_xor(s, 16);
        s += __shfl_xor(s, 32);      // all lanes now hold gs_{l&15}
        gsv = fast_tanh(s);
    }

    // final: grp0 -> q16 (scaled), grp1 -> k16, grp2 -> g16, grp3 -> gswz.
    // All shuffles executed convergently (before/outside divergent stores).
    const int grp = l >> 4;
    const int r = i4 >> 2, c = i4 & 3;
    float gq[4];
    #pragma unroll
    for (int j = 0; j < 4; ++j) gq[j] = __shfl(gsv, r * 4 + j);
    const float temp = (cosf(ent[0]) + cosf(ent[1]) + cosf(ent[2])) * (1.f / 3.f);

    float v;
    if (grp == 0) {
        v = 0.f;
        #pragma unroll
        for (int j = 0; j < 4; ++j) v = fmaf(gq[j], rot[j * 4 + c], v);
        v *= temp * 0.25f;
    } else if (grp == 1) {
        v = 0.f;
        #pragma unroll
        for (int j = 0; j < 4; ++j) v = fmaf(gq[j], rot[c * 4 + j], v);
    } else {
        v = gsv;
    }
    const float vn = __shfl_xor(v, 1);   // convergent pair exchange

    if (grp == 3) {
        const int tile = b >> 4, lc = b & 15;
        gswz[tile * 256 + (((lc >> 2) * 16) + i4) * 4 + (lc & 3)] = (_Float16)gsv;
    } else if ((i4 & 1) == 0) {
        const h2v pv = pk(v, vn);
        if (grp == 0)      ((h2v*)q16)[b * 8 + (i4 >> 1)] = pv;
        else if (grp == 1) ((h2v*)k16)[b * 8 + (i4 >> 1)] = pv;
        else               ((h2v*)g16)[b * 8 + (i4 >> 1)] = pv;
    }
}

// ---------------------------------------------------------------------------
// Kernel 2 v5: MFMA flash attention, 16 waves/block (no BN fusion — the
// contended-counter variant regressed 10 us; see R1 post-mortem).
// ---------------------------------------------------------------------------
__global__ __launch_bounds__(1024) void k_attn(
    const _Float16* __restrict__ q16, const _Float16* __restrict__ k16,
    const _Float16* __restrict__ g16, const _Float16* __restrict__ gswz,
    const float* __restrict__ rw, const float* __restrict__ rb,
    const float* __restrict__ cw, const float* __restrict__ cb,
    float* __restrict__ outp, int B)
{
    __shared__ f4 lO[16][64];
    __shared__ float lm[16][16];
    __shared__ float ll[16][16];

    const int t = threadIdx.x;
    const int lane = t & 63;
    const int w = t >> 6;
    const int rt = blockIdx.x;
    const int r = lane & 15;
    const int q = lane >> 4;
    const f4 fzero = {0.f, 0.f, 0.f, 0.f};

    const h4 qf = *(const h4*)(q16 + ((size_t)(rt * 16 + r)) * 16 + q * 4);

    float m = -1e30f, lp = 0.f;
    f4 O = fzero;

    const int strip = B >> 4;
    const int cbeg = w * strip;
    for (int ci = 0; ci < strip; ci += 16) {
        const int c0 = cbeg + ci;
        const h4 kf = *(const h4*)(k16 + ((size_t)(c0 + r)) * 16 + q * 4);
        const f4 st = mfma16x16(kf, qf, fzero);

        float mx = fmaxf(fmaxf(st[0], st[1]), fmaxf(st[2], st[3]));
        mx = fmaxf(mx, __shfl_xor(mx, 16));
        mx = fmaxf(mx, __shfl_xor(mx, 32));
        if (__ballot(mx > m)) {
            const float mn = fmaxf(m, mx);
            const float a = exp2f((m - mn) * LOG2E);
            lp *= a;
            O[0] *= a; O[1] *= a; O[2] *= a; O[3] *= a;
            m = mn;
        }
        const float p0 = exp2f((st[0] - m) * LOG2E);
        const float p1 = exp2f((st[1] - m) * LOG2E);
        const float p2 = exp2f((st[2] - m) * LOG2E);
        const float p3 = exp2f((st[3] - m) * LOG2E);
        lp += (p0 + p1) + (p2 + p3);

        union { h4 v; h2v p[2]; } u;
        u.p[0] = pk(p0, p1);
        u.p[1] = pk(p2, p3);
        const h4 gf = *(const h4*)(gswz + (size_t)((c0 >> 4)) * 256 + lane * 4);
        O = mfma16x16(gf, u.v, O);
    }
    lp += __shfl_xor(lp, 16);
    lp += __shfl_xor(lp, 32);

    lO[w][lane] = O;
    if (lane < 16) { lm[w][lane] = m; ll[w][lane] = lp; }
    __syncthreads();

    if (w == 0) {
        float M = lm[0][r];
        #pragma unroll
        for (int ww = 1; ww < 16; ++ww) M = fmaxf(M, lm[ww][r]);
        float L = 0.f;
        f4 Om = fzero;
        #pragma unroll
        for (int ww = 0; ww < 16; ++ww) {
            const float f = exp2f((lm[ww][r] - M) * LOG2E);
            L = fmaf(ll[ww][r], f, L);
            const f4 ow = lO[ww][lane];
            Om[0] = fmaf(ow[0], f, Om[0]);
            Om[1] = fmaf(ow[1], f, Om[1]);
            Om[2] = fmaf(ow[2], f, Om[2]);
            Om[3] = fmaf(ow[3], f, Om[3]);
        }
        const float il = 1.f / L;
        const h4 gr = *(const h4*)(g16 + ((size_t)(rt * 16 + r)) * 16 + q * 4);

        float rv[2];
        #pragma unroll
        for (int c = 0; c < 2; ++c) {
            float s = 0.f;
            #pragma unroll
            for (int j = 0; j < 4; ++j) {
                s = fmaf((float)gr[j], rw[c * 32 + q * 4 + j], s);
                s = fmaf(Om[j] * il, rw[c * 32 + 16 + q * 4 + j], s);
            }
            s += __shfl_xor(s, 16);
            s += __shfl_xor(s, 32);
            rv[c] = s + rb[c];
        }
        if (q == 0) {
            float2 o;
            o.x = cb[0] + cw[0] * rv[0] + cw[1] * rv[1];
            o.y = cb[1] + cw[2] * rv[0] + cw[3] * rv[1];
            ((float2*)outp)[rt * 16 + r] = o;
        }
    }
}

// ---------------------------------------------------------------------------
// Kernel 3: BatchNorm1d(2), batch stats, in-place on d_out.
// ---------------------------------------------------------------------------
__global__ __launch_bounds__(1024) void k_bn(
    float* __restrict__ data, const float* __restrict__ gamma,
    const float* __restrict__ beta, int B)
{
    __shared__ float red[16][4];
    __shared__ float coef[4];
    const int t = threadIdx.x;
    float s0 = 0.f, s1 = 0.f, q0 = 0.f, q1 = 0.f;
    for (int i = t; i < B; i += 1024) {
        const float2 v = ((const float2*)data)[i];
        s0 += v.x; q0 += v.x * v.x;
        s1 += v.y; q1 += v.y * v.y;
    }
    #pragma unroll
    for (int off = 32; off; off >>= 1) {
        s0 += __shfl_xor(s0, off); q0 += __shfl_xor(q0, off);
        s1 += __shfl_xor(s1, off); q1 += __shfl_xor(q1, off);
    }
    if ((t & 63) == 0) {
        red[t >> 6][0] = s0; red[t >> 6][1] = q0;
        red[t >> 6][2] = s1; red[t >> 6][3] = q1;
    }
    __syncthreads();
    if (t == 0) {
        float S0 = 0.f, Q0 = 0.f, S1 = 0.f, Q1 = 0.f;
        for (int w = 0; w < 16; ++w) {
            S0 += red[w][0]; Q0 += red[w][1]; S1 += red[w][2]; Q1 += red[w][3];
        }
        const float inv = 1.f / (float)B;
        const float mu0 = S0 * inv, mu1 = S1 * inv;
        const float v0 = Q0 * inv - mu0 * mu0;
        const float v1 = Q1 * inv - mu1 * mu1;
        const float sc0 = gamma[0] * rsqrtf(v0 + 1e-5f);
        const float sc1 = gamma[1] * rsqrtf(v1 + 1e-5f);
        coef[0] = sc0; coef[1] = beta[0] - mu0 * sc0;
        coef[2] = sc1; coef[3] = beta[1] - mu1 * sc1;
    }
    __syncthreads();
    const float sc0 = coef[0], sh0 = coef[1], sc1 = coef[2], sh1 = coef[3];
    for (int i = t; i < B; i += 1024) {
        float2 v = ((const float2*)data)[i];
        v.x = fmaf(v.x, sc0, sh0);
        v.y = fmaf(v.y, sc1, sh1);
        ((float2*)data)[i] = v;
    }
}

extern "C" void kernel_launch(void* const* d_in, const int* in_sizes, int n_in,
                              void* d_out, int out_size, void* d_ws, size_t ws_size,
                              hipStream_t stream)
{
    (void)n_in; (void)out_size; (void)ws_size;
    const float* x   = (const float*)d_in[0];
    const float* w1  = (const float*)d_in[1];
    const float* b1  = (const float*)d_in[2];
    const float* w2  = (const float*)d_in[3];
    const float* b2  = (const float*)d_in[4];
    const float* w3  = (const float*)d_in[5];
    const float* b3  = (const float*)d_in[6];
    const float* gw1 = (const float*)d_in[7];
    const float* gw2 = (const float*)d_in[8];
    const float* rot = (const float*)d_in[9];
    const float* ent = (const float*)d_in[10];
    const float* rw  = (const float*)d_in[11];
    const float* rbv = (const float*)d_in[12];
    const float* cw  = (const float*)d_in[13];
    const float* cbv = (const float*)d_in[14];
    const float* gam = (const float*)d_in[15];
    const float* bet = (const float*)d_in[16];

    const int B = in_sizes[0] / (32 * 32);   // 4096

    _Float16* q16  = (_Float16*)d_ws;                 // [B][16]
    _Float16* k16  = q16 + (size_t)B * 16;            // [B][16]
    _Float16* g16  = k16 + (size_t)B * 16;            // [B][16]
    _Float16* gswz = g16 + (size_t)B * 16;            // [B/16][64][4]
    _Float16* w2f  = gswz + (size_t)B * 16;           // 1536 halves
    _Float16* w3f  = w2f + 1536;                      // 5120 halves
    h2v*      w1p  = (h2v*)(w3f + 5120);              // 24 pairs
    float*    w1t  = (float*)(w1p + 24);              // 24 floats
    float* pre = (float*)d_out;

    k_pack<<<1, 256, 0, stream>>>(w1, w2, w3, w2f, w3f, w1p, w1t);
    k_cnn<<<B, 256, 0, stream>>>(x, w1p, w1t, b1, w2f, b2, w3f, b3, gw1, gw2,
                                 rot, ent, q16, k16, g16, gswz);
    k_attn<<<B / 16, 1024, 0, stream>>>(q16, k16, g16, gswz, rw, rbv, cw, cbv,
                                        pre, B);
    k_bn<<<1, 1024, 0, stream>>>(pre, gam, bet, B);
}

// Round 3
// 132.756 us; speedup vs baseline: 1.1277x; 1.0571x over previous
//
#include <hip/hip_runtime.h>
#include <math.h>

#define LOG2E 1.4426950408889634f

typedef _Float16 h2v __attribute__((ext_vector_type(2)));
typedef _Float16 h4  __attribute__((ext_vector_type(4)));
typedef _Float16 h8  __attribute__((ext_vector_type(8)));
typedef float    f4  __attribute__((ext_vector_type(4)));

__device__ __forceinline__ h2v pk(float a, float b) {
    return __builtin_bit_cast(h2v, __builtin_amdgcn_cvt_pkrtz(a, b));
}

__device__ __forceinline__ f4 mfma16x32(h8 a, h8 b, f4 c) {
    return __builtin_amdgcn_mfma_f32_16x16x32_f16(a, b, c, 0, 0, 0);
}

// Legacy (pre-gfx950) intrinsic name has NO underscore before f16.
__device__ __forceinline__ f4 mfma16x16(h4 a, h4 b, f4 c) {
    return __builtin_amdgcn_mfma_f32_16x16x16f16(a, b, c, 0, 0, 0);
}

__device__ __forceinline__ float fast_tanh(float x) {
    const float xc = fminf(fmaxf(x, -15.f), 15.f);
    const float t = exp2f(xc * (2.f * LOG2E));
    return (t - 1.f) * __builtin_amdgcn_rcpf(t + 1.f);
}

// ---------------------------------------------------------------------------
// Prelude: pack conv weights. w2f/w3f in MFMA A-fragment order (fp16);
// w1 as (col0,col1) h2 pairs + fp32 col2 for the conv1 dot2 path.
// Also precomputes the attention temperature scale (3x cosf) ONCE instead
// of per-CNN-block (4096x).
// ---------------------------------------------------------------------------
__global__ __launch_bounds__(256) void k_pack(
    const float* __restrict__ w1,
    const float* __restrict__ w2, const float* __restrict__ w3,
    const float* __restrict__ ent,
    _Float16* __restrict__ w2f, _Float16* __restrict__ w3f,
    h2v* __restrict__ w1p, float* __restrict__ w1t,
    float* __restrict__ tsc)
{
    if (threadIdx.x == 0) {
        const float temp = (cosf(ent[0]) + cosf(ent[1]) + cosf(ent[2])) * (1.f / 3.f);
        tsc[0] = temp * 0.25f;
    }
    if (threadIdx.x < 24) {
        const int oc = threadIdx.x / 3, ky = threadIdx.x % 3;
        w1p[threadIdx.x] = pk(w1[oc * 9 + ky * 3 + 0], w1[oc * 9 + ky * 3 + 1]);
        w1t[threadIdx.x] = w1[oc * 9 + ky * 3 + 2];
    }
    for (int idx = threadIdx.x; idx < 1536; idx += 256) {
        const int j = idx & 7;
        const int lane = (idx >> 3) & 63;
        const int c = idx >> 9;
        const int oc = lane & 15;
        const int s = c * 4 + (lane >> 4);
        w2f[idx] = (s < 9) ? (_Float16)w2[oc * 72 + j * 9 + s] : (_Float16)0.f;
    }
    for (int idx = threadIdx.x; idx < 5120; idx += 256) {
        const int j = idx & 7;
        const int lane = (idx >> 3) & 63;
        const int rest = idx >> 9;          // mt*5 + c
        const int mt = rest / 5;
        const int oc = mt * 16 + (lane & 15);
        const int kk = (lane >> 4) * 8 + j;
        const int ic = kk & 15;
        const int sh = (rest - mt * 5) * 2 + (kk >> 4);
        w3f[idx] = (sh < 9) ? (_Float16)w3[oc * 144 + ic * 9 + sh] : (_Float16)0.f;
    }
}

// ---------------------------------------------------------------------------
// Kernel 1 v10: per-image CNN. conv2/conv3 MFMA B-fragments read DIRECTLY
// from the p1c/p2hc cell arrays. Tail (mean+MLP+q/k/g) runs on wave 0
// ONLY, fully shuffle-based. x global load issued BEFORE halo zeroing so
// HBM latency overlaps the LDS writes. temp scale read from ws (1 scalar).
// ---------------------------------------------------------------------------
__global__ __launch_bounds__(256) void k_cnn(
    const float* __restrict__ x,
    const h2v* __restrict__ w1p, const float* __restrict__ w1t,
    const float* __restrict__ b1,
    const _Float16* __restrict__ w2f, const float* __restrict__ b2,
    const _Float16* __restrict__ w3f, const float* __restrict__ b3,
    const float* __restrict__ gw1,
    const float* __restrict__ gw2,
    const float* __restrict__ rot,
    const float* __restrict__ tsc,
    _Float16* __restrict__ q16, _Float16* __restrict__ k16,
    _Float16* __restrict__ g16, _Float16* __restrict__ gswz)
{
    __shared__ __align__(16) char smem[4624 + 5184 + 3200 + 256];
    float* xs   = (float*)smem;                       // 34x34 fp32
    h8*  p1c    = (h8*)(smem + 4624);                 // [18][18] cells of 8 halves
    h8*  p2hc   = (h8*)(smem + 4624 + 5184);          // [10][10] cells, 2 h8 each
    h4*  p2h4   = (h4*)(smem + 4624 + 5184);
    float* fsum = (float*)(smem + 4624 + 5184 + 3200);    // 64 floats

    const int t = threadIdx.x;
    const int b = blockIdx.x;
    const int lane = t & 63;
    const int w = __builtin_amdgcn_readfirstlane(t >> 6);
    const int nn = lane & 15;
    const int kq = lane >> 4;

    const h8 hzero = (h8)(_Float16)0.f;
    const f4 fzero = {0.f, 0.f, 0.f, 0.f};

    // ---- issue the global load FIRST; its latency hides under halo stores
    const float4 v = ((const float4*)(x + (size_t)b * 1024))[t];

    // ---- halo-only zeroing (interiors fully overwritten) ----
    if (t < 132) {
        int r, c;
        if (t < 34)       { r = 0;  c = t; }
        else if (t < 68)  { r = 33; c = t - 34; }
        else if (t < 100) { r = t - 68 + 1;  c = 0; }
        else              { r = t - 100 + 1; c = 33; }
        xs[r * 34 + c] = 0.f;
    } else if (t < 200) {
        const int u = t - 132;
        int r, c;
        if (u < 18)      { r = 0;  c = u; }
        else if (u < 36) { r = 17; c = u - 18; }
        else if (u < 52) { r = u - 36 + 1; c = 0; }
        else             { r = u - 52 + 1; c = 17; }
        p1c[r * 18 + c] = hzero;
    } else if (t < 236) {
        const int u = t - 200;
        int r, c;
        if (u < 10)      { r = 0; c = u; }
        else if (u < 20) { r = 9; c = u - 10; }
        else if (u < 28) { r = u - 20 + 1; c = 0; }
        else             { r = u - 28 + 1; c = 9; }
        p2hc[(r * 10 + c) * 2 + 0] = hzero;
        p2hc[(r * 10 + c) * 2 + 1] = hzero;
    }
    {
        const int row = t >> 3;
        const int col = (t & 7) << 2;
        float* dst = &xs[(row + 1) * 34 + col + 1];
        dst[0] = v.x; dst[1] = v.y; dst[2] = v.z; dst[3] = v.w;
    }
    __syncthreads();

    // ---- stage 1: conv1 via fdot2 + relu + maxpool2 -> p1 cells ----
    {
        const int px = t & 15, py = t >> 4;
        float pa[4][4];
        #pragma unroll
        for (int iy = 0; iy < 4; ++iy)
            #pragma unroll
            for (int ix = 0; ix < 4; ++ix)
                pa[iy][ix] = xs[(2 * py + iy) * 34 + (2 * px + ix)];
        h2v pA[4], pB[4];
        #pragma unroll
        for (int r = 0; r < 4; ++r) {
            pA[r] = pk(pa[r][0], pa[r][1]);
            pB[r] = pk(pa[r][1], pa[r][2]);
        }

        float r8[8];
        #pragma unroll
        for (int oc = 0; oc < 8; ++oc) {
            const h2v wp0 = w1p[oc * 3 + 0], wp1 = w1p[oc * 3 + 1], wp2 = w1p[oc * 3 + 2];
            const float wt0 = w1t[oc * 3 + 0], wt1 = w1t[oc * 3 + 1], wt2 = w1t[oc * 3 + 2];
            const float bb = b1[oc];
            float mx = -1e30f;
            #pragma unroll
            for (int sy = 0; sy < 2; ++sy) {
                float s0 = bb, s1 = bb;
                s0 = __builtin_amdgcn_fdot2(pA[sy],     wp0, s0, false);
                s0 = __builtin_amdgcn_fdot2(pA[sy + 1], wp1, s0, false);
                s0 = __builtin_amdgcn_fdot2(pA[sy + 2], wp2, s0, false);
                s0 = fmaf(pa[sy][2], wt0, s0);
                s0 = fmaf(pa[sy + 1][2], wt1, s0);
                s0 = fmaf(pa[sy + 2][2], wt2, s0);
                s1 = __builtin_amdgcn_fdot2(pB[sy],     wp0, s1, false);
                s1 = __builtin_amdgcn_fdot2(pB[sy + 1], wp1, s1, false);
                s1 = __builtin_amdgcn_fdot2(pB[sy + 2], wp2, s1, false);
                s1 = fmaf(pa[sy][3], wt0, s1);
                s1 = fmaf(pa[sy + 1][3], wt1, s1);
                s1 = fmaf(pa[sy + 2][3], wt2, s1);
                mx = fmaxf(mx, fmaxf(s0, s1));
            }
            r8[oc] = fmaxf(mx, 0.f);
        }
        union { h8 v; h2v p[4]; } u;
        #pragma unroll
        for (int ocp = 0; ocp < 4; ++ocp) u.p[ocp] = pk(r8[2 * ocp], r8[2 * ocp + 1]);
        p1c[(py + 1) * 18 + (px + 1)] = u.v;
    }

    h8 a2[3];
    #pragma unroll
    for (int c = 0; c < 3; ++c) a2[c] = ((const h8*)w2f)[c * 64 + lane];

    __syncthreads();   // p1c ready

    // ---- conv2(8->16) as GEMM: B-fragments read directly from p1c ----
    f4 accp[4] = {fzero, fzero, fzero, fzero};
    #pragma unroll
    for (int c = 0; c < 3; ++c) {
        const int s = c * 4 + kq;
        const int ky = (s < 9) ? s / 3 : 0;
        const int kx = (s < 9) ? s % 3 : 0;
        #pragma unroll
        for (int p = 0; p < 4; ++p) {
            h8 bf = hzero;
            if (s < 9) bf = p1c[(4 * w + p + ky) * 18 + (nn + kx)];
            accp[p] = mfma16x32(a2[c], bf, accp[p]);
        }
    }

    // ---- conv2 epilogue: +bias, relu, 2x2 maxpool -> p2 cells ----
    {
        float bq[4];
        #pragma unroll
        for (int r = 0; r < 4; ++r) bq[r] = b2[kq * 4 + r];
        #pragma unroll
        for (int i = 0; i < 2; ++i) {
            float m2[4];
            #pragma unroll
            for (int r = 0; r < 4; ++r) {
                const float v0 = fmaxf(accp[2 * i][r] + bq[r], 0.f);
                const float v1 = fmaxf(accp[2 * i + 1][r] + bq[r], 0.f);
                float mv = fmaxf(v0, v1);
                mv = fmaxf(mv, __shfl_xor(mv, 1));
                m2[r] = mv;
            }
            if ((lane & 1) == 0) {
                const int px = nn >> 1;
                const int py = 2 * w + i;
                union { h4 v; h2v p[2]; } u;
                u.p[0] = pk(m2[0], m2[1]);
                u.p[1] = pk(m2[2], m2[3]);
                p2h4[((py + 1) * 10 + (px + 1)) * 4 + kq] = u.v;
            }
        }
    }

    const int mt = w >> 1;
    const int nt0 = (w & 1) * 2;
    h8 a3[5];
    #pragma unroll
    for (int c = 0; c < 5; ++c) a3[c] = ((const h8*)w3f)[(mt * 5 + c) * 64 + lane];

    __syncthreads();   // p2hc ready

    // ---- conv3(16->32) as GEMM: B-fragments read directly from p2hc ----
    f4 acc3[2] = {fzero, fzero};
    #pragma unroll
    for (int c = 0; c < 5; ++c) {
        const int shv = 2 * c + (kq >> 1);
        const int hh = kq & 1;
        const int ky = (shv < 9) ? ((shv * 11) >> 5) : 0;
        const int kx = (shv < 9) ? (shv - 3 * ky) : 0;
        #pragma unroll
        for (int p = 0; p < 2; ++p) {
            const int pos = (nt0 + p) * 16 + nn;
            const int yy = pos >> 3, xx = pos & 7;
            h8 bf = hzero;
            if (shv < 9) bf = p2hc[((yy + ky) * 10 + (xx + kx)) * 2 + hh];
            acc3[p] = mfma16x32(a3[c], bf, acc3[p]);
        }
    }

    // ---- conv3 epilogue: +bias, relu, spatial sum ----
    {
        float bq[4];
        #pragma unroll
        for (int r = 0; r < 4; ++r) bq[r] = b3[mt * 16 + kq * 4 + r];
        float sv[4];
        #pragma unroll
        for (int r = 0; r < 4; ++r) {
            float s = fmaxf(acc3[0][r] + bq[r], 0.f) + fmaxf(acc3[1][r] + bq[r], 0.f);
            #pragma unroll
            for (int off = 1; off < 16; off <<= 1) s += __shfl_xor(s, off);
            sv[r] = s;
        }
        if (nn == 0) {
            const f4 pack = {sv[0], sv[1], sv[2], sv[3]};
            ((f4*)fsum)[mt * 8 + (w & 1) * 4 + kq] = pack;
        }
    }
    __syncthreads();   // fsum ready

    // ---- wave-0-only tail: mean + MLP head, shuffle-based, no barriers ----
    if (w != 0) return;

    const float qscale = tsc[0];     // issued early; uniform scalar load

    const int l = t;                 // 0..63
    const int i5 = l & 31;
    // fs: per-channel mean (channels 0..31 held by lanes l&31)
    const float fsv = (fsum[(i5 >> 4) * 32 + (i5 & 15)] +
                       fsum[(i5 >> 4) * 32 + 16 + (i5 & 15)]) * (1.f / 64.f);

    // as = tanh(gw1 @ fs): 32 outputs, j-range split across lane halves
    float asv;
    {
        const int h = l >> 5;        // 0 or 1
        float s = 0.f;
        #pragma unroll
        for (int q4 = 0; q4 < 4; ++q4) {
            const float4 wv = ((const float4*)gw1)[i5 * 8 + h * 4 + q4];
            s = fmaf(wv.x, __shfl(fsv, h * 16 + q4 * 4 + 0), s);
            s = fmaf(wv.y, __shfl(fsv, h * 16 + q4 * 4 + 1), s);
            s = fmaf(wv.z, __shfl(fsv, h * 16 + q4 * 4 + 2), s);
            s = fmaf(wv.w, __shfl(fsv, h * 16 + q4 * 4 + 3), s);
        }
        s += __shfl_xor(s, 32);      // all lanes now hold as_{l&31}
        asv = fast_tanh(s);
    }

    // gs = tanh(gw2 @ as): 16 outputs, j-range split across lane quads
    const int i4 = l & 15;
    float gsv;
    {
        const int h = l >> 4;        // 0..3
        float s = 0.f;
        #pragma unroll
        for (int q4 = 0; q4 < 2; ++q4) {
            const float4 wv = ((const float4*)gw2)[i4 * 8 + h * 2 + q4];
            s = fmaf(wv.x, __shfl(asv, h * 8 + q4 * 4 + 0), s);
            s = fmaf(wv.y, __shfl(asv, h * 8 + q4 * 4 + 1), s);
            s = fmaf(wv.z, __shfl(asv, h * 8 + q4 * 4 + 2), s);
            s = fmaf(wv.w, __shfl(asv, h * 8 + q4 * 4 + 3), s);
        }
        s += __shfl_xor(s, 16);
        s += __shfl_xor(s, 32);      // all lanes now hold gs_{l&15}
        gsv = fast_tanh(s);
    }

    // final: grp0 -> q16 (scaled), grp1 -> k16, grp2 -> g16, grp3 -> gswz.
    // All shuffles executed convergently (before/outside divergent stores).
    const int grp = l >> 4;
    const int r = i4 >> 2, c = i4 & 3;
    float gq[4];
    #pragma unroll
    for (int j = 0; j < 4; ++j) gq[j] = __shfl(gsv, r * 4 + j);

    float v2;
    if (grp == 0) {
        v2 = 0.f;
        #pragma unroll
        for (int j = 0; j < 4; ++j) v2 = fmaf(gq[j], rot[j * 4 + c], v2);
        v2 *= qscale;
    } else if (grp == 1) {
        v2 = 0.f;
        #pragma unroll
        for (int j = 0; j < 4; ++j) v2 = fmaf(gq[j], rot[c * 4 + j], v2);
    } else {
        v2 = gsv;
    }
    const float vn = __shfl_xor(v2, 1);   // convergent pair exchange

    if (grp == 3) {
        const int tile = b >> 4, lc = b & 15;
        gswz[tile * 256 + (((lc >> 2) * 16) + i4) * 4 + (lc & 3)] = (_Float16)gsv;
    } else if ((i4 & 1) == 0) {
        const h2v pv = pk(v2, vn);
        if (grp == 0)      ((h2v*)q16)[b * 8 + (i4 >> 1)] = pv;
        else if (grp == 1) ((h2v*)k16)[b * 8 + (i4 >> 1)] = pv;
        else               ((h2v*)g16)[b * 8 + (i4 >> 1)] = pv;
    }
}

// ---------------------------------------------------------------------------
// Kernel 2 v7: MFMA flash attention, 16 waves/block, software-pipelined
// kf/gf loads (next tile prefetched while current tile computes).
// ---------------------------------------------------------------------------
__global__ __launch_bounds__(1024) void k_attn(
    const _Float16* __restrict__ q16, const _Float16* __restrict__ k16,
    const _Float16* __restrict__ g16, const _Float16* __restrict__ gswz,
    const float* __restrict__ rw, const float* __restrict__ rb,
    const float* __restrict__ cw, const float* __restrict__ cb,
    float* __restrict__ outp, int B)
{
    __shared__ f4 lO[16][64];
    __shared__ float lm[16][16];
    __shared__ float ll[16][16];

    const int t = threadIdx.x;
    const int lane = t & 63;
    const int w = t >> 6;
    const int rt = blockIdx.x;
    const int r = lane & 15;
    const int q = lane >> 4;
    const f4 fzero = {0.f, 0.f, 0.f, 0.f};

    const h4 qf = *(const h4*)(q16 + ((size_t)(rt * 16 + r)) * 16 + q * 4);

    float m = -1e30f, lp = 0.f;
    f4 O = fzero;

    const int strip = B >> 4;
    const int cbeg = w * strip;

    h4 kf = *(const h4*)(k16 + ((size_t)(cbeg + r)) * 16 + q * 4);
    h4 gf = *(const h4*)(gswz + (size_t)(cbeg >> 4) * 256 + lane * 4);

    for (int ci = 0; ci < strip; ci += 16) {
        // prefetch next tile (dummy = first tile on the last iteration)
        const int cnext = (ci + 16 < strip) ? (cbeg + ci + 16) : cbeg;
        const h4 kf_n = *(const h4*)(k16 + ((size_t)(cnext + r)) * 16 + q * 4);
        const h4 gf_n = *(const h4*)(gswz + (size_t)(cnext >> 4) * 256 + lane * 4);

        const f4 st = mfma16x16(kf, qf, fzero);

        float mx = fmaxf(fmaxf(st[0], st[1]), fmaxf(st[2], st[3]));
        mx = fmaxf(mx, __shfl_xor(mx, 16));
        mx = fmaxf(mx, __shfl_xor(mx, 32));
        if (__ballot(mx > m)) {
            const float mn = fmaxf(m, mx);
            const float a = exp2f((m - mn) * LOG2E);
            lp *= a;
            O[0] *= a; O[1] *= a; O[2] *= a; O[3] *= a;
            m = mn;
        }
        const float p0 = exp2f((st[0] - m) * LOG2E);
        const float p1 = exp2f((st[1] - m) * LOG2E);
        const float p2 = exp2f((st[2] - m) * LOG2E);
        const float p3 = exp2f((st[3] - m) * LOG2E);
        lp += (p0 + p1) + (p2 + p3);

        union { h4 v; h2v p[2]; } u;
        u.p[0] = pk(p0, p1);
        u.p[1] = pk(p2, p3);
        O = mfma16x16(gf, u.v, O);

        kf = kf_n;
        gf = gf_n;
    }
    lp += __shfl_xor(lp, 16);
    lp += __shfl_xor(lp, 32);

    lO[w][lane] = O;
    if (lane < 16) { lm[w][lane] = m; ll[w][lane] = lp; }
    __syncthreads();

    if (w == 0) {
        float M = lm[0][r];
        #pragma unroll
        for (int ww = 1; ww < 16; ++ww) M = fmaxf(M, lm[ww][r]);
        float L = 0.f;
        f4 Om = fzero;
        #pragma unroll
        for (int ww = 0; ww < 16; ++ww) {
            const float f = exp2f((lm[ww][r] - M) * LOG2E);
            L = fmaf(ll[ww][r], f, L);
            const f4 ow = lO[ww][lane];
            Om[0] = fmaf(ow[0], f, Om[0]);
            Om[1] = fmaf(ow[1], f, Om[1]);
            Om[2] = fmaf(ow[2], f, Om[2]);
            Om[3] = fmaf(ow[3], f, Om[3]);
        }
        const float il = 1.f / L;
        const h4 gr = *(const h4*)(g16 + ((size_t)(rt * 16 + r)) * 16 + q * 4);

        float rv[2];
        #pragma unroll
        for (int c = 0; c < 2; ++c) {
            float s = 0.f;
            #pragma unroll
            for (int j = 0; j < 4; ++j) {
                s = fmaf((float)gr[j], rw[c * 32 + q * 4 + j], s);
                s = fmaf(Om[j] * il, rw[c * 32 + 16 + q * 4 + j], s);
            }
            s += __shfl_xor(s, 16);
            s += __shfl_xor(s, 32);
            rv[c] = s + rb[c];
        }
        if (q == 0) {
            float2 o;
            o.x = cb[0] + cw[0] * rv[0] + cw[1] * rv[1];
            o.y = cb[1] + cw[2] * rv[0] + cw[3] * rv[1];
            ((float2*)outp)[rt * 16 + r] = o;
        }
    }
}

// ---------------------------------------------------------------------------
// Kernel 3: BatchNorm1d(2), batch stats, in-place on d_out.
// ---------------------------------------------------------------------------
__global__ __launch_bounds__(1024) void k_bn(
    float* __restrict__ data, const float* __restrict__ gamma,
    const float* __restrict__ beta, int B)
{
    __shared__ float red[16][4];
    __shared__ float coef[4];
    const int t = threadIdx.x;
    float s0 = 0.f, s1 = 0.f, q0 = 0.f, q1 = 0.f;
    for (int i = t; i < B; i += 1024) {
        const float2 v = ((const float2*)data)[i];
        s0 += v.x; q0 += v.x * v.x;
        s1 += v.y; q1 += v.y * v.y;
    }
    #pragma unroll
    for (int off = 32; off; off >>= 1) {
        s0 += __shfl_xor(s0, off); q0 += __shfl_xor(q0, off);
        s1 += __shfl_xor(s1, off); q1 += __shfl_xor(q1, off);
    }
    if ((t & 63) == 0) {
        red[t >> 6][0] = s0; red[t >> 6][1] = q0;
        red[t >> 6][2] = s1; red[t >> 6][3] = q1;
    }
    __syncthreads();
    if (t == 0) {
        float S0 = 0.f, Q0 = 0.f, S1 = 0.f, Q1 = 0.f;
        for (int w = 0; w < 16; ++w) {
            S0 += red[w][0]; Q0 += red[w][1]; S1 += red[w][2]; Q1 += red[w][3];
        }
        const float inv = 1.f / (float)B;
        const float mu0 = S0 * inv, mu1 = S1 * inv;
        const float v0 = Q0 * inv - mu0 * mu0;
        const float v1 = Q1 * inv - mu1 * mu1;
        const float sc0 = gamma[0] * rsqrtf(v0 + 1e-5f);
        const float sc1 = gamma[1] * rsqrtf(v1 + 1e-5f);
        coef[0] = sc0; coef[1] = beta[0] - mu0 * sc0;
        coef[2] = sc1; coef[3] = beta[1] - mu1 * sc1;
    }
    __syncthreads();
    const float sc0 = coef[0], sh0 = coef[1], sc1 = coef[2], sh1 = coef[3];
    for (int i = t; i < B; i += 1024) {
        float2 v = ((const float2*)data)[i];
        v.x = fmaf(v.x, sc0, sh0);
        v.y = fmaf(v.y, sc1, sh1);
        ((float2*)data)[i] = v;
    }
}

extern "C" void kernel_launch(void* const* d_in, const int* in_sizes, int n_in,
                              void* d_out, int out_size, void* d_ws, size_t ws_size,
                              hipStream_t stream)
{
    (void)n_in; (void)out_size; (void)ws_size;
    const float* x   = (const float*)d_in[0];
    const float* w1  = (const float*)d_in[1];
    const float* b1  = (const float*)d_in[2];
    const float* w2  = (const float*)d_in[3];
    const float* b2  = (const float*)d_in[4];
    const float* w3  = (const float*)d_in[5];
    const float* b3  = (const float*)d_in[6];
    const float* gw1 = (const float*)d_in[7];
    const float* gw2 = (const float*)d_in[8];
    const float* rot = (const float*)d_in[9];
    const float* ent = (const float*)d_in[10];
    const float* rw  = (const float*)d_in[11];
    const float* rbv = (const float*)d_in[12];
    const float* cw  = (const float*)d_in[13];
    const float* cbv = (const float*)d_in[14];
    const float* gam = (const float*)d_in[15];
    const float* bet = (const float*)d_in[16];

    const int B = in_sizes[0] / (32 * 32);   // 4096

    _Float16* q16  = (_Float16*)d_ws;                 // [B][16]
    _Float16* k16  = q16 + (size_t)B * 16;            // [B][16]
    _Float16* g16  = k16 + (size_t)B * 16;            // [B][16]
    _Float16* gswz = g16 + (size_t)B * 16;            // [B/16][64][4]
    _Float16* w2f  = gswz + (size_t)B * 16;           // 1536 halves
    _Float16* w3f  = w2f + 1536;                      // 5120 halves
    h2v*      w1p  = (h2v*)(w3f + 5120);              // 24 pairs
    float*    w1t  = (float*)(w1p + 24);              // 24 floats
    float*    tsc  = w1t + 24;                        // temp*0.25 scale
    float* pre = (float*)d_out;

    k_pack<<<1, 256, 0, stream>>>(w1, w2, w3, ent, w2f, w3f, w1p, w1t, tsc);
    k_cnn<<<B, 256, 0, stream>>>(x, w1p, w1t, b1, w2f, b2, w3f, b3, gw1, gw2,
                                 rot, tsc, q16, k16, g16, gswz);
    k_attn<<<B / 16, 1024, 0, stream>>>(q16, k16, g16, gswz, rw, rbv, cw, cbv,
                                        pre, B);
    k_bn<<<1, 1024, 0, stream>>>(pre, gam, bet, B);
}